// Round 7
// baseline (349.638 us; speedup 1.0000x reference)
//
#include <hip/hip_runtime.h>
#include <hip/hip_bf16.h>
#include <math.h>

#define B_ 2
#define L_ 2048
#define DM_ 1024
#define DC_ 512
#define NH_ 8
#define DH_ 64
#define MR_ (B_*L_)   // 4096 rows
#define BH_ (B_*NH_)  // 16

typedef unsigned short u16;
typedef unsigned int u32;
typedef __attribute__((ext_vector_type(8))) short bf16x8;
typedef __attribute__((ext_vector_type(4))) float f32x4;

static __device__ __forceinline__ u16 f2bf(float x) {
  union { float f; u32 u; } v; v.f = x;
  u32 r = (v.u + 0x7fffu + ((v.u >> 16) & 1u)) >> 16;  // RNE
  return (u16)r;
}
static __device__ __forceinline__ float bf2f(u16 x) {
  union { u32 u; float f; } v; v.u = ((u32)x) << 16;
  return v.f;
}

// ---------------------------------------------------------------------------
// One-shot fp32 -> bf16 conversion: x1 (from src, stride 1024), Wq, Wk, Wst,
// Wout. Grid = 3840 x 256, 4 elems (one float4) per thread.
// ---------------------------------------------------------------------------
__global__ __launch_bounds__(256) void cvt_k(
    const float* __restrict__ src,
    const float* __restrict__ Wq, const float* __restrict__ Wk,
    const float* __restrict__ Wst, const float* __restrict__ Wout,
    u16* __restrict__ x1b, u16* __restrict__ Wqb, u16* __restrict__ Wkb,
    u16* __restrict__ Wstb, u16* __restrict__ Woutb)
{
  int v = blockIdx.x * 256 + threadIdx.x;
  if (v < 524288) {
    const int m = v >> 7, c = (v & 127) << 2;
    float4 f = *(const float4*)(src + (size_t)m * DM_ + c);
    *(ushort4*)(x1b + (size_t)m * DC_ + c) =
        make_ushort4(f2bf(f.x), f2bf(f.y), f2bf(f.z), f2bf(f.w));
    return;
  }
  v -= 524288;
  const float* sp; u16* dp;
  if (v < 65536)       { sp = Wq;   dp = Wqb; }
  else if (v < 131072) { sp = Wk;   dp = Wkb;   v -= 65536; }
  else if (v < 196608) { sp = Wst;  dp = Wstb;  v -= 131072; }
  else                 { sp = Wout; dp = Woutb; v -= 196608; }
  float4 f = *(const float4*)(sp + (size_t)v * 4);
  *(ushort4*)(dp + (size_t)v * 4) =
      make_ushort4(f2bf(f.x), f2bf(f.y), f2bf(f.z), f2bf(f.w));
}

// ---------------------------------------------------------------------------
// bf16 MFMA GEMM: C = A @ W^T + bias. Block tile 128 x BN, BK=32, 256 thr =
// 4 waves. MODE 0: bf16 heads layout; MODE 1: fused gate -> bf16 [m][n];
// MODE 2: A k-split (A | A2), fp32 out.
// ---------------------------------------------------------------------------
template<int MODE, int BN>
__global__ __launch_bounds__(256) void mgemm_k(
    const u16* __restrict__ A, const u16* __restrict__ A2,
    const u16* __restrict__ W, const float* __restrict__ bias,
    const float* __restrict__ src, u16* __restrict__ Ob,
    float* __restrict__ Of, int Ndim, int Kdim)
{
  constexpr int MF = (BN == 128) ? 4 : 2;   // M-frags per wave
  constexpr int WC = BN / 64;               // wave columns
  __shared__ u16 As[128 * 40];
  __shared__ u16 Ws[BN * 40];
  const int tid = threadIdx.x;
  const int wid = tid >> 6, lane = tid & 63;
  const int lr = lane & 15, lg = lane >> 4;
  const int wr = wid / WC, wc = wid % WC;
  const int m0 = blockIdx.y << 7;
  const int n0 = blockIdx.x * BN;

  f32x4 acc[MF][4];
#pragma unroll
  for (int mi = 0; mi < MF; ++mi)
#pragma unroll
    for (int ni = 0; ni < 4; ++ni)
      acc[mi][ni] = (f32x4){0.f, 0.f, 0.f, 0.f};

  for (int k0 = 0; k0 < Kdim; k0 += 32) {
    {
      const int row = tid >> 1, seg = (tid & 1) << 4;
      const u16* ap;
      if (MODE == 2)
        ap = (k0 < 512) ? A  + (size_t)(m0 + row) * 512 + k0 + seg
                        : A2 + (size_t)(m0 + row) * 512 + (k0 - 512) + seg;
      else
        ap = A + (size_t)(m0 + row) * Kdim + k0 + seg;
      *(bf16x8*)&As[row * 40 + seg]     = *(const bf16x8*)ap;
      *(bf16x8*)&As[row * 40 + seg + 8] = *(const bf16x8*)(ap + 8);
    }
    if (BN == 128) {
      const int row = tid >> 1, seg = (tid & 1) << 4;
      const u16* wp = W + (size_t)(n0 + row) * Kdim + k0 + seg;
      *(bf16x8*)&Ws[row * 40 + seg]     = *(const bf16x8*)wp;
      *(bf16x8*)&Ws[row * 40 + seg + 8] = *(const bf16x8*)(wp + 8);
    } else {
      const int row = tid >> 2, seg = (tid & 3) << 3;
      *(bf16x8*)&Ws[row * 40 + seg] =
          *(const bf16x8*)(W + (size_t)(n0 + row) * Kdim + k0 + seg);
    }
    __syncthreads();
    bf16x8 af[MF], bfr[4];
#pragma unroll
    for (int mi = 0; mi < MF; ++mi)
      af[mi] = *(bf16x8*)&As[(wr * (MF * 16) + mi * 16 + lr) * 40 + lg * 8];
#pragma unroll
    for (int ni = 0; ni < 4; ++ni)
      bfr[ni] = *(bf16x8*)&Ws[(wc * 64 + ni * 16 + lr) * 40 + lg * 8];
#pragma unroll
    for (int mi = 0; mi < MF; ++mi)
#pragma unroll
      for (int ni = 0; ni < 4; ++ni)
        acc[mi][ni] = __builtin_amdgcn_mfma_f32_16x16x32_bf16(
            af[mi], bfr[ni], acc[mi][ni], 0, 0, 0);
    __syncthreads();
  }

#pragma unroll
  for (int mi = 0; mi < MF; ++mi)
#pragma unroll
    for (int ni = 0; ni < 4; ++ni)
#pragma unroll
      for (int r = 0; r < 4; ++r) {
        const int m = m0 + wr * (MF * 16) + mi * 16 + lg * 4 + r;
        const int n = n0 + wc * 64 + ni * 16 + lr;
        const float v = acc[mi][ni][r] + bias[n];
        if (MODE == 0) {
          const int b = m >> 11, l = m & (L_ - 1), h = n >> 6, d = n & (DH_ - 1);
          Ob[((size_t)(b * NH_ + h) * L_ + l) * DH_ + d] = f2bf(v);
        } else if (MODE == 1) {
          const float x2 = src[(size_t)m * DM_ + DC_ + n];
          const float s = 1.f / (1.f + __expf(-v));
          Ob[(size_t)m * DC_ + n] = f2bf(s * tanhf(x2) + (1.f - s) * x2);
        } else {
          Of[(size_t)m * Ndim + n] = v;
        }
      }
}

// ---------------------------------------------------------------------------
// Saliency conv1d
// ---------------------------------------------------------------------------
__global__ __launch_bounds__(256) void conv_k(
    const float* __restrict__ src, const float* __restrict__ cw,
    const float* __restrict__ cb, float* __restrict__ sal)
{
  __shared__ float xs[34][260];
  const int b = blockIdx.y;
  const int l0 = blockIdx.x << 5;
  const int tid = threadIdx.x;
  const int li = tid >> 3, h = tid & 7;
  float acc = cb[h];
  for (int c0 = 0; c0 < DC_; c0 += 256) {
    __syncthreads();
    for (int t = tid; t < 34*64; t += 256) {
      const int r = t >> 6;
      const int c4 = (t & 63) << 2;
      const int l = l0 - 1 + r;
      float4 v = make_float4(0.f, 0.f, 0.f, 0.f);
      if (l >= 0 && l < L_)
        v = *(const float4*)(src + (size_t)(b*L_ + l) * DM_ + c0 + c4);
      *(float4*)&xs[r][c4] = v;
    }
    __syncthreads();
    for (int c = 0; c < 256; ++c) {
      const float* w = cw + ((size_t)h * DC_ + c0 + c) * 3;
      acc += xs[li+0][c]*w[0] + xs[li+1][c]*w[1] + xs[li+2][c]*w[2];
    }
  }
  sal[(size_t)(b*NH_ + h) * L_ + l0 + li] = acc;
}

// ---------------------------------------------------------------------------
// MFMA attention, restructured:
//  sweep1: NO LDS, NO barriers. QK B-frags straight from global (L1-resident),
//          exp + rowsum -> invS in-lane.
//  sweep2: Kt (K^T for PV) built from global via coalesced u16 gathers,
//          double-buffered with register prefetch -> ONE barrier per tile.
//          QK frags from global; Ps (p-hat bf16) is same-wave LDS only.
// Fragment maps (m89/m91): A/B: lane&15 = M/N, (lane>>4)*8+j = K.
//                          D: col = lane&15, row = (lane>>4)*4 + reg.
// ---------------------------------------------------------------------------
__global__ __launch_bounds__(256) void attn_k(
    const u16* __restrict__ Qh, const u16* __restrict__ Kh,
    const float* __restrict__ sal, float* __restrict__ attn,
    u16* __restrict__ ctxb)
{
  __shared__ u16 Kt[2][64*72];
  __shared__ u16 Ps[64*72];
  __shared__ float sal_s[L_];

  const int tid = threadIdx.x;
  const int wid = tid >> 6;
  const int lane = tid & 63;
  const int lr = lane & 15;
  const int lg = lane >> 4;
  const int bh = blockIdx.y;
  const int q0 = blockIdx.x << 6;
  const u16* Kbase = Kh + (size_t)bh * L_ * DH_;
  const u16* Qp = Qh + ((size_t)bh * L_ + q0) * DH_;

  // stage sal row-block for this bh (2048 f32 = 8KB), once
  {
    const float4* sp = (const float4*)(sal + (size_t)bh * L_);
    float4* dp = (float4*)sal_s;
#pragma unroll
    for (int i = 0; i < 2; ++i)
      dp[tid + i*256] = sp[tid + i*256];
  }
  // Q frags direct from global (row = q0 + wid*16 + lr)
  bf16x8 qf[2];
  qf[0] = *(const bf16x8*)(Qp + (size_t)(wid*16 + lr) * DH_ + lg*8);
  qf[1] = *(const bf16x8*)(Qp + (size_t)(wid*16 + lr) * DH_ + 32 + lg*8);
  __syncthreads();  // sal_s visible

  // ---------------- sweep 1: rowsums (no LDS, no barriers) ----------------
  float rs[4] = {0.f, 0.f, 0.f, 0.f};
#pragma unroll 2
  for (int m0 = 0; m0 < L_; m0 += 64) {
#pragma unroll
    for (int ms = 0; ms < 4; ++ms) {
      f32x4 acc = {0.f, 0.f, 0.f, 0.f};
#pragma unroll
      for (int ks = 0; ks < 2; ++ks) {
        bf16x8 kf = *(const bf16x8*)(Kbase + (size_t)(m0 + ms*16 + lr) * DH_ + ks*32 + lg*8);
        acc = __builtin_amdgcn_mfma_f32_16x16x32_bf16(qf[ks], kf, acc, 0, 0, 0);
      }
      const float sl = sal_s[m0 + ms*16 + lr];
#pragma unroll
      for (int r = 0; r < 4; ++r)
        rs[r] += __expf(fmaf(acc[r], 0.125f, sl));
    }
  }
  // reduce over the 16 col-lanes; invS replicated into every lane of the row
#pragma unroll
  for (int r = 0; r < 4; ++r) {
    float v = rs[r];
    v += __shfl_xor(v, 1); v += __shfl_xor(v, 2);
    v += __shfl_xor(v, 4); v += __shfl_xor(v, 8);
    rs[r] = 1.0f / v;
  }

  // ---------------- sweep 2: attn store + PV ----------------
  f32x4 pvacc[4] = {{0.f,0.f,0.f,0.f},{0.f,0.f,0.f,0.f},
                    {0.f,0.f,0.f,0.f},{0.f,0.f,0.f,0.f}};
  // Kt register prefetch: thread covers d=lane, m-rows wid*16..+15 (as 4x4)
  ushort4 kreg[4];
#pragma unroll
  for (int qd = 0; qd < 4; ++qd) {
    const int mq = wid*4 + qd;
    ushort4 t;
    t.x = Kbase[(size_t)(mq*4+0) * DH_ + lane];
    t.y = Kbase[(size_t)(mq*4+1) * DH_ + lane];
    t.z = Kbase[(size_t)(mq*4+2) * DH_ + lane];
    t.w = Kbase[(size_t)(mq*4+3) * DH_ + lane];
    kreg[qd] = t;
  }

  for (int t = 0; t < L_/64; ++t) {
    const int m0 = t << 6;
    u16* KtC = Kt[t & 1];
    // commit prefetched K^T tile
#pragma unroll
    for (int qd = 0; qd < 4; ++qd)
      *(ushort4*)&KtC[lane*72 + (wid*4 + qd)*4] = kreg[qd];
    // issue next tile's gathers (in flight across the barrier + compute)
    if (t < L_/64 - 1) {
      const int mn = m0 + 64;
#pragma unroll
      for (int qd = 0; qd < 4; ++qd) {
        const int mq = wid*4 + qd;
        ushort4 tt;
        tt.x = Kbase[(size_t)(mn + mq*4+0) * DH_ + lane];
        tt.y = Kbase[(size_t)(mn + mq*4+1) * DH_ + lane];
        tt.z = Kbase[(size_t)(mn + mq*4+2) * DH_ + lane];
        tt.w = Kbase[(size_t)(mn + mq*4+3) * DH_ + lane];
        kreg[qd] = tt;
      }
    }
    __syncthreads();  // KtC visible (single barrier per tile)

    // QK^T (B-frags from global) + normalized p -> Ps (same-wave)
#pragma unroll
    for (int ms = 0; ms < 4; ++ms) {
      f32x4 acc = {0.f, 0.f, 0.f, 0.f};
#pragma unroll
      for (int ks = 0; ks < 2; ++ks) {
        bf16x8 kf = *(const bf16x8*)(Kbase + (size_t)(m0 + ms*16 + lr) * DH_ + ks*32 + lg*8);
        acc = __builtin_amdgcn_mfma_f32_16x16x32_bf16(qf[ks], kf, acc, 0, 0, 0);
      }
      const float sl = sal_s[m0 + ms*16 + lr];
#pragma unroll
      for (int r = 0; r < 4; ++r) {
        const float ph = __expf(fmaf(acc[r], 0.125f, sl)) * rs[r];
        Ps[(wid*16 + lg*4 + r)*72 + ms*16 + lr] = f2bf(ph);
      }
    }
    // attn store: own strip from Ps, coalesced float4 stores
    {
      const int qr = lane >> 2;            // 0..15
      const int mseg = (lane & 3) << 4;    // 0,16,32,48
      bf16x8 v0 = *(bf16x8*)&Ps[(wid*16 + qr)*72 + mseg];
      bf16x8 v1 = *(bf16x8*)&Ps[(wid*16 + qr)*72 + mseg + 8];
      float* dst = attn + ((size_t)bh * L_ + q0 + wid*16 + qr) * L_ + m0 + mseg;
#pragma unroll
      for (int u = 0; u < 2; ++u) {
        bf16x8 v = u ? v1 : v0;
        float4 f0 = make_float4(bf2f((u16)v[0]), bf2f((u16)v[1]),
                                bf2f((u16)v[2]), bf2f((u16)v[3]));
        float4 f1 = make_float4(bf2f((u16)v[4]), bf2f((u16)v[5]),
                                bf2f((u16)v[6]), bf2f((u16)v[7]));
        *(float4*)(dst + u*8)     = f0;
        *(float4*)(dst + u*8 + 4) = f1;
      }
    }
    // PV: ctx += P @ K  (A = Ps rows, B = Kt rows)
#pragma unroll
    for (int ks = 0; ks < 2; ++ks) {
      bf16x8 pa = *(bf16x8*)&Ps[(wid*16 + lr)*72 + ks*32 + lg*8];
#pragma unroll
      for (int ds = 0; ds < 4; ++ds) {
        bf16x8 kb = *(bf16x8*)&KtC[(ds*16 + lr)*72 + ks*32 + lg*8];
        pvacc[ds] = __builtin_amdgcn_mfma_f32_16x16x32_bf16(pa, kb, pvacc[ds], 0, 0, 0);
      }
    }
    __syncthreads();  // all waves done with KtC before t+2 overwrites
  }
  // ctx store [b, l, h*64+d] as bf16
  const int b = bh >> 3, h = bh & 7;
#pragma unroll
  for (int ds = 0; ds < 4; ++ds)
#pragma unroll
    for (int r = 0; r < 4; ++r)
      ctxb[((size_t)(b*L_ + q0 + wid*16 + lg*4 + r)) * DC_ + h*DH_ + ds*16 + lr] =
          f2bf(pvacc[ds][r]);
}

// ---------------------------------------------------------------------------
extern "C" void kernel_launch(void* const* d_in, const int* in_sizes, int n_in,
                              void* d_out, int out_size, void* d_ws, size_t ws_size,
                              hipStream_t stream)
{
  const float* src   = (const float*)d_in[0];
  const float* Wq    = (const float*)d_in[1];
  const float* bq    = (const float*)d_in[2];
  const float* Wk    = (const float*)d_in[3];
  const float* bk    = (const float*)d_in[4];
  const float* convw = (const float*)d_in[5];
  const float* convb = (const float*)d_in[6];
  const float* Wst   = (const float*)d_in[7];
  const float* bst   = (const float*)d_in[8];
  const float* Wout  = (const float*)d_in[9];
  const float* bout  = (const float*)d_in[10];

  float* out  = (float*)d_out;                 // fp32: reference output dtype
  float* attn = out + (size_t)MR_ * DM_;       // output (4,194,304), then attn (67,108,864)

  u16*   x1b   = (u16*)d_ws;                    // [4096][512]
  u16*   Qh    = x1b   + (size_t)MR_ * DC_;     // [16][2048][64]
  u16*   Kh    = Qh    + (size_t)BH_ * L_ * DH_;
  u16*   ctxb  = Kh    + (size_t)BH_ * L_ * DH_;// [4096][512]
  u16*   y2b   = ctxb  + (size_t)MR_ * DC_;     // [4096][512]
  u16*   Wqb   = y2b   + (size_t)MR_ * DC_;     // [512][512]
  u16*   Wkb   = Wqb   + (size_t)DC_ * DC_;
  u16*   Wstb  = Wkb   + (size_t)DC_ * DC_;
  u16*   Woutb = Wstb  + (size_t)DC_ * DC_;     // [1024][1024]
  float* salb  = (float*)(Woutb + (size_t)DM_ * DM_); // [16][2048]

  (void)in_sizes; (void)n_in; (void)out_size; (void)ws_size;

  cvt_k<<<dim3(3840), 256, 0, stream>>>(src, Wq, Wk, Wst, Wout,
                                        x1b, Wqb, Wkb, Wstb, Woutb);
  mgemm_k<0,64><<<dim3(8, 32), 256, 0, stream>>>(x1b, nullptr, Wqb, bq, nullptr, Qh, nullptr, DC_, DC_);
  mgemm_k<0,64><<<dim3(8, 32), 256, 0, stream>>>(x1b, nullptr, Wkb, bk, nullptr, Kh, nullptr, DC_, DC_);
  conv_k<<<dim3(L_/32, B_), 256, 0, stream>>>(src, convw, convb, salb);
  attn_k<<<dim3(L_/64, BH_), 256, 0, stream>>>(Qh, Kh, salb, attn, ctxb);
  mgemm_k<1,64><<<dim3(8, 32), 256, 0, stream>>>(ctxb, nullptr, Wstb, bst, src, y2b, nullptr, DC_, DC_);
  mgemm_k<2,128><<<dim3(8, 32), 256, 0, stream>>>(x1b, y2b, Woutb, bout, nullptr, nullptr, out, DM_, DM_);
}

// Round 8
// 258.478 us; speedup vs baseline: 1.3527x; 1.3527x over previous
//
#include <hip/hip_runtime.h>
#include <hip/hip_bf16.h>
#include <math.h>

#define B_ 2
#define L_ 2048
#define DM_ 1024
#define DC_ 512
#define NH_ 8
#define DH_ 64
#define MR_ (B_*L_)   // 4096 rows
#define BH_ (B_*NH_)  // 16

typedef unsigned short u16;
typedef unsigned int u32;
typedef __attribute__((ext_vector_type(8))) short bf16x8;
typedef __attribute__((ext_vector_type(4))) float f32x4;

static __device__ __forceinline__ u16 f2bf(float x) {
  union { float f; u32 u; } v; v.f = x;
  u32 r = (v.u + 0x7fffu + ((v.u >> 16) & 1u)) >> 16;  // RNE
  return (u16)r;
}
static __device__ __forceinline__ float bf2f(u16 x) {
  union { u32 u; float f; } v; v.u = ((u32)x) << 16;
  return v.f;
}

// ---------------------------------------------------------------------------
// One-shot fp32 -> bf16 conversion: x1, Wq, Wk, Wst, Wout.
// ---------------------------------------------------------------------------
__global__ __launch_bounds__(256) void cvt_k(
    const float* __restrict__ src,
    const float* __restrict__ Wq, const float* __restrict__ Wk,
    const float* __restrict__ Wst, const float* __restrict__ Wout,
    u16* __restrict__ x1b, u16* __restrict__ Wqb, u16* __restrict__ Wkb,
    u16* __restrict__ Wstb, u16* __restrict__ Woutb)
{
  int v = blockIdx.x * 256 + threadIdx.x;
  if (v < 524288) {
    const int m = v >> 7, c = (v & 127) << 2;
    float4 f = *(const float4*)(src + (size_t)m * DM_ + c);
    *(ushort4*)(x1b + (size_t)m * DC_ + c) =
        make_ushort4(f2bf(f.x), f2bf(f.y), f2bf(f.z), f2bf(f.w));
    return;
  }
  v -= 524288;
  const float* sp; u16* dp;
  if (v < 65536)       { sp = Wq;   dp = Wqb; }
  else if (v < 131072) { sp = Wk;   dp = Wkb;   v -= 65536; }
  else if (v < 196608) { sp = Wst;  dp = Wstb;  v -= 131072; }
  else                 { sp = Wout; dp = Woutb; v -= 196608; }
  float4 f = *(const float4*)(sp + (size_t)v * 4);
  *(ushort4*)(dp + (size_t)v * 4) =
      make_ushort4(f2bf(f.x), f2bf(f.y), f2bf(f.z), f2bf(f.w));
}

// ---------------------------------------------------------------------------
// K transpose: KhT[bh][d][m] from Kh[bh][m][d]. Block = (bh, 64-m tile).
// ---------------------------------------------------------------------------
__global__ __launch_bounds__(256) void tr_k(const u16* __restrict__ Kh,
                                            u16* __restrict__ KhT)
{
  __shared__ u16 T[64*72];
  const int tid = threadIdx.x;
  const int bh = blockIdx.x >> 5, mt = blockIdx.x & 31;
  const int m0 = mt << 6;
  const u16* Kb = Kh + ((size_t)bh * L_ + m0) * DH_;
  const int r = tid >> 2, c = (tid & 3) << 4;
  *(bf16x8*)&T[r*72 + c]     = *(const bf16x8*)(Kb + (size_t)r * DH_ + c);
  *(bf16x8*)&T[r*72 + c + 8] = *(const bf16x8*)(Kb + (size_t)r * DH_ + c + 8);
  __syncthreads();
  const int d = tid >> 2, mc = (tid & 3) << 4;
  bf16x8 v0, v1;
#pragma unroll
  for (int i = 0; i < 8; ++i) {
    v0[i] = (short)T[(mc + i)*72 + d];
    v1[i] = (short)T[(mc + 8 + i)*72 + d];
  }
  u16* dst = KhT + ((size_t)bh * DH_ + d) * L_ + m0 + mc;
  *(bf16x8*)dst = v0;
  *(bf16x8*)(dst + 8) = v1;
}

// ---------------------------------------------------------------------------
// bf16 MFMA GEMM: C = A @ W^T + bias. (unchanged from round 6)
// ---------------------------------------------------------------------------
template<int MODE, int BN>
__global__ __launch_bounds__(256) void mgemm_k(
    const u16* __restrict__ A, const u16* __restrict__ A2,
    const u16* __restrict__ W, const float* __restrict__ bias,
    const float* __restrict__ src, u16* __restrict__ Ob,
    float* __restrict__ Of, int Ndim, int Kdim)
{
  constexpr int MF = (BN == 128) ? 4 : 2;
  constexpr int WC = BN / 64;
  __shared__ u16 As[128 * 40];
  __shared__ u16 Ws[BN * 40];
  const int tid = threadIdx.x;
  const int wid = tid >> 6, lane = tid & 63;
  const int lr = lane & 15, lg = lane >> 4;
  const int wr = wid / WC, wc = wid % WC;
  const int m0 = blockIdx.y << 7;
  const int n0 = blockIdx.x * BN;

  f32x4 acc[MF][4];
#pragma unroll
  for (int mi = 0; mi < MF; ++mi)
#pragma unroll
    for (int ni = 0; ni < 4; ++ni)
      acc[mi][ni] = (f32x4){0.f, 0.f, 0.f, 0.f};

  for (int k0 = 0; k0 < Kdim; k0 += 32) {
    {
      const int row = tid >> 1, seg = (tid & 1) << 4;
      const u16* ap;
      if (MODE == 2)
        ap = (k0 < 512) ? A  + (size_t)(m0 + row) * 512 + k0 + seg
                        : A2 + (size_t)(m0 + row) * 512 + (k0 - 512) + seg;
      else
        ap = A + (size_t)(m0 + row) * Kdim + k0 + seg;
      *(bf16x8*)&As[row * 40 + seg]     = *(const bf16x8*)ap;
      *(bf16x8*)&As[row * 40 + seg + 8] = *(const bf16x8*)(ap + 8);
    }
    if (BN == 128) {
      const int row = tid >> 1, seg = (tid & 1) << 4;
      const u16* wp = W + (size_t)(n0 + row) * Kdim + k0 + seg;
      *(bf16x8*)&Ws[row * 40 + seg]     = *(const bf16x8*)wp;
      *(bf16x8*)&Ws[row * 40 + seg + 8] = *(const bf16x8*)(wp + 8);
    } else {
      const int row = tid >> 2, seg = (tid & 3) << 3;
      *(bf16x8*)&Ws[row * 40 + seg] =
          *(const bf16x8*)(W + (size_t)(n0 + row) * Kdim + k0 + seg);
    }
    __syncthreads();
    bf16x8 af[MF], bfr[4];
#pragma unroll
    for (int mi = 0; mi < MF; ++mi)
      af[mi] = *(bf16x8*)&As[(wr * (MF * 16) + mi * 16 + lr) * 40 + lg * 8];
#pragma unroll
    for (int ni = 0; ni < 4; ++ni)
      bfr[ni] = *(bf16x8*)&Ws[(wc * 64 + ni * 16 + lr) * 40 + lg * 8];
#pragma unroll
    for (int mi = 0; mi < MF; ++mi)
#pragma unroll
      for (int ni = 0; ni < 4; ++ni)
        acc[mi][ni] = __builtin_amdgcn_mfma_f32_16x16x32_bf16(
            af[mi], bfr[ni], acc[mi][ni], 0, 0, 0);
    __syncthreads();
  }

#pragma unroll
  for (int mi = 0; mi < MF; ++mi)
#pragma unroll
    for (int ni = 0; ni < 4; ++ni)
#pragma unroll
      for (int r = 0; r < 4; ++r) {
        const int m = m0 + wr * (MF * 16) + mi * 16 + lg * 4 + r;
        const int n = n0 + wc * 64 + ni * 16 + lr;
        const float v = acc[mi][ni][r] + bias[n];
        if (MODE == 0) {
          const int b = m >> 11, l = m & (L_ - 1), h = n >> 6, d = n & (DH_ - 1);
          Ob[((size_t)(b * NH_ + h) * L_ + l) * DH_ + d] = f2bf(v);
        } else if (MODE == 1) {
          const float x2 = src[(size_t)m * DM_ + DC_ + n];
          const float s = 1.f / (1.f + __expf(-v));
          Ob[(size_t)m * DC_ + n] = f2bf(s * tanhf(x2) + (1.f - s) * x2);
        } else {
          Of[(size_t)m * Ndim + n] = v;
        }
      }
}

// ---------------------------------------------------------------------------
// Saliency conv1d (unchanged)
// ---------------------------------------------------------------------------
__global__ __launch_bounds__(256) void conv_k(
    const float* __restrict__ src, const float* __restrict__ cw,
    const float* __restrict__ cb, float* __restrict__ sal)
{
  __shared__ float xs[34][260];
  const int b = blockIdx.y;
  const int l0 = blockIdx.x << 5;
  const int tid = threadIdx.x;
  const int li = tid >> 3, h = tid & 7;
  float acc = cb[h];
  for (int c0 = 0; c0 < DC_; c0 += 256) {
    __syncthreads();
    for (int t = tid; t < 34*64; t += 256) {
      const int r = t >> 6;
      const int c4 = (t & 63) << 2;
      const int l = l0 - 1 + r;
      float4 v = make_float4(0.f, 0.f, 0.f, 0.f);
      if (l >= 0 && l < L_)
        v = *(const float4*)(src + (size_t)(b*L_ + l) * DM_ + c0 + c4);
      *(float4*)&xs[r][c4] = v;
    }
    __syncthreads();
    for (int c = 0; c < 256; ++c) {
      const float* w = cw + ((size_t)h * DC_ + c0 + c) * 3;
      acc += xs[li+0][c]*w[0] + xs[li+1][c]*w[1] + xs[li+2][c]*w[2];
    }
  }
  sal[(size_t)(b*NH_ + h) * L_ + l0 + li] = acc;
}

// ---------------------------------------------------------------------------
// MFMA attention v3: latency-hiding pipeline, ONE barrier per tile.
// Per tile: issue global loads (regs) -> compute (long) -> commit regs->LDS
// (other buffer) -> barrier. Loads land during compute; the barrier's vmcnt
// drain is then free. Kn (K rows) and KT (K^T rows, precomputed by tr_k) both
// staged coalesced. Ps is same-wave LDS (lgkm only).
// ---------------------------------------------------------------------------
__global__ __launch_bounds__(256) void attn_k(
    const u16* __restrict__ Qh, const u16* __restrict__ Kh,
    const u16* __restrict__ KhT, const float* __restrict__ sal,
    float* __restrict__ attn, u16* __restrict__ ctxb)
{
  __shared__ u16 Kn[2][64*72];
  __shared__ u16 KT[2][64*72];
  __shared__ u16 Ps[64*72];
  __shared__ float sal_t[2][64];

  const int tid = threadIdx.x;
  const int wid = tid >> 6, lane = tid & 63;
  const int lr = lane & 15, lg = lane >> 4;
  // XCD-bijective swizzle: 512 blocks = 8 xcd x 64; same-bh blocks cluster
  const int lin = blockIdx.x;
  const int swz = (lin & 7) * 64 + (lin >> 3);
  const int bh = swz >> 5, q0 = (swz & 31) << 6;

  const u16* Kb   = Kh  + (size_t)bh * L_ * DH_;
  const u16* KTb  = KhT + (size_t)bh * DH_ * L_;
  const float* salp = sal + (size_t)bh * L_;

  // Q frags direct from global
  const u16* Qp = Qh + ((size_t)bh * L_ + q0) * DH_;
  bf16x8 qf[2];
  qf[0] = *(const bf16x8*)(Qp + (size_t)(wid*16 + lr) * DH_ + lg*8);
  qf[1] = *(const bf16x8*)(Qp + (size_t)(wid*16 + lr) * DH_ + 32 + lg*8);

  const int sr = tid >> 2;            // staging row 0..63
  const int sc = (tid & 3) << 4;      // staging chunk (16 u16)
  bf16x8 ka0, ka1, kt0, kt1;
  float sv = 0.f;

  // ================= sweep 1: rowsums =================
  ka0 = *(const bf16x8*)(Kb + (size_t)sr * DH_ + sc);
  ka1 = *(const bf16x8*)(Kb + (size_t)sr * DH_ + sc + 8);
  if (tid < 64) sv = salp[tid];
  *(bf16x8*)&Kn[0][sr*72 + sc]     = ka0;
  *(bf16x8*)&Kn[0][sr*72 + sc + 8] = ka1;
  if (tid < 64) sal_t[0][tid] = sv;
  __syncthreads();

  float rs[4] = {0.f, 0.f, 0.f, 0.f};
  for (int t = 0; t < 32; ++t) {
    const int cur = t & 1;
    if (t < 31) {  // issue next-tile loads: they land during compute below
      const int mn = (t + 1) << 6;
      ka0 = *(const bf16x8*)(Kb + (size_t)(mn + sr) * DH_ + sc);
      ka1 = *(const bf16x8*)(Kb + (size_t)(mn + sr) * DH_ + sc + 8);
      if (tid < 64) sv = salp[mn + tid];
    }
#pragma unroll
    for (int ms = 0; ms < 4; ++ms) {
      f32x4 acc = {0.f, 0.f, 0.f, 0.f};
#pragma unroll
      for (int ks = 0; ks < 2; ++ks) {
        bf16x8 kf = *(bf16x8*)&Kn[cur][(ms*16 + lr)*72 + ks*32 + lg*8];
        acc = __builtin_amdgcn_mfma_f32_16x16x32_bf16(qf[ks], kf, acc, 0, 0, 0);
      }
      const float sl = sal_t[cur][ms*16 + lr];
#pragma unroll
      for (int r = 0; r < 4; ++r)
        rs[r] += __expf(fmaf(acc[r], 0.125f, sl));
    }
    if (t < 31) {
      *(bf16x8*)&Kn[cur^1][sr*72 + sc]     = ka0;
      *(bf16x8*)&Kn[cur^1][sr*72 + sc + 8] = ka1;
      if (tid < 64) sal_t[cur^1][tid] = sv;
    }
    __syncthreads();
  }
  // reduce over 16 col-lanes -> invS in every lane of the row
#pragma unroll
  for (int r = 0; r < 4; ++r) {
    float v = rs[r];
    v += __shfl_xor(v, 1); v += __shfl_xor(v, 2);
    v += __shfl_xor(v, 4); v += __shfl_xor(v, 8);
    rs[r] = 1.0f / v;
  }

  // ================= sweep 2: attn store + PV =================
  ka0 = *(const bf16x8*)(Kb + (size_t)sr * DH_ + sc);
  ka1 = *(const bf16x8*)(Kb + (size_t)sr * DH_ + sc + 8);
  kt0 = *(const bf16x8*)(KTb + (size_t)sr * L_ + sc);
  kt1 = *(const bf16x8*)(KTb + (size_t)sr * L_ + sc + 8);
  if (tid < 64) sv = salp[tid];
  *(bf16x8*)&Kn[0][sr*72 + sc]     = ka0;
  *(bf16x8*)&Kn[0][sr*72 + sc + 8] = ka1;
  *(bf16x8*)&KT[0][sr*72 + sc]     = kt0;
  *(bf16x8*)&KT[0][sr*72 + sc + 8] = kt1;
  if (tid < 64) sal_t[0][tid] = sv;
  __syncthreads();

  f32x4 pvacc[4] = {{0.f,0.f,0.f,0.f},{0.f,0.f,0.f,0.f},
                    {0.f,0.f,0.f,0.f},{0.f,0.f,0.f,0.f}};
  for (int t = 0; t < 32; ++t) {
    const int cur = t & 1;
    const int m0 = t << 6;
    if (t < 31) {  // issue next-tile loads early
      const int mn = m0 + 64;
      ka0 = *(const bf16x8*)(Kb + (size_t)(mn + sr) * DH_ + sc);
      ka1 = *(const bf16x8*)(Kb + (size_t)(mn + sr) * DH_ + sc + 8);
      kt0 = *(const bf16x8*)(KTb + (size_t)sr * L_ + mn + sc);
      kt1 = *(const bf16x8*)(KTb + (size_t)sr * L_ + mn + sc + 8);
      if (tid < 64) sv = salp[mn + tid];
    }
    // QK^T + normalized p -> Ps (same-wave strip)
#pragma unroll
    for (int ms = 0; ms < 4; ++ms) {
      f32x4 acc = {0.f, 0.f, 0.f, 0.f};
#pragma unroll
      for (int ks = 0; ks < 2; ++ks) {
        bf16x8 kf = *(bf16x8*)&Kn[cur][(ms*16 + lr)*72 + ks*32 + lg*8];
        acc = __builtin_amdgcn_mfma_f32_16x16x32_bf16(qf[ks], kf, acc, 0, 0, 0);
      }
      const float sl = sal_t[cur][ms*16 + lr];
#pragma unroll
      for (int r = 0; r < 4; ++r) {
        const float ph = __expf(fmaf(acc[r], 0.125f, sl)) * rs[r];
        Ps[(wid*16 + lg*4 + r)*72 + ms*16 + lr] = f2bf(ph);
      }
    }
    // attn store: own strip from Ps, coalesced float4 stores
    {
      const int qr = lane >> 2;            // 0..15
      const int mseg = (lane & 3) << 4;    // 0,16,32,48
      bf16x8 v0 = *(bf16x8*)&Ps[(wid*16 + qr)*72 + mseg];
      bf16x8 v1 = *(bf16x8*)&Ps[(wid*16 + qr)*72 + mseg + 8];
      float* dst = attn + ((size_t)bh * L_ + q0 + wid*16 + qr) * L_ + m0 + mseg;
#pragma unroll
      for (int u = 0; u < 2; ++u) {
        bf16x8 v = u ? v1 : v0;
        float4 f0 = make_float4(bf2f((u16)v[0]), bf2f((u16)v[1]),
                                bf2f((u16)v[2]), bf2f((u16)v[3]));
        float4 f1 = make_float4(bf2f((u16)v[4]), bf2f((u16)v[5]),
                                bf2f((u16)v[6]), bf2f((u16)v[7]));
        *(float4*)(dst + u*8)     = f0;
        *(float4*)(dst + u*8 + 4) = f1;
      }
    }
    // PV: ctx += P @ K  (A = Ps rows, B = KT rows)
#pragma unroll
    for (int ks = 0; ks < 2; ++ks) {
      bf16x8 pa = *(bf16x8*)&Ps[(wid*16 + lr)*72 + ks*32 + lg*8];
#pragma unroll
      for (int ds = 0; ds < 4; ++ds) {
        bf16x8 kb = *(bf16x8*)&KT[cur][(ds*16 + lr)*72 + ks*32 + lg*8];
        pvacc[ds] = __builtin_amdgcn_mfma_f32_16x16x32_bf16(pa, kb, pvacc[ds], 0, 0, 0);
      }
    }
    if (t < 31) {  // commit next tile into the other buffer
      *(bf16x8*)&Kn[cur^1][sr*72 + sc]     = ka0;
      *(bf16x8*)&Kn[cur^1][sr*72 + sc + 8] = ka1;
      *(bf16x8*)&KT[cur^1][sr*72 + sc]     = kt0;
      *(bf16x8*)&KT[cur^1][sr*72 + sc + 8] = kt1;
      if (tid < 64) sal_t[cur^1][tid] = sv;
      __syncthreads();
    }
  }
  // ctx store [b, l, h*64+d] as bf16
  const int b = bh >> 3, h = bh & 7;
#pragma unroll
  for (int ds = 0; ds < 4; ++ds)
#pragma unroll
    for (int r = 0; r < 4; ++r)
      ctxb[((size_t)(b*L_ + q0 + wid*16 + lg*4 + r)) * DC_ + h*DH_ + ds*16 + lr] =
          f2bf(pvacc[ds][r]);
}

// ---------------------------------------------------------------------------
extern "C" void kernel_launch(void* const* d_in, const int* in_sizes, int n_in,
                              void* d_out, int out_size, void* d_ws, size_t ws_size,
                              hipStream_t stream)
{
  const float* src   = (const float*)d_in[0];
  const float* Wq    = (const float*)d_in[1];
  const float* bq    = (const float*)d_in[2];
  const float* Wk    = (const float*)d_in[3];
  const float* bk    = (const float*)d_in[4];
  const float* convw = (const float*)d_in[5];
  const float* convb = (const float*)d_in[6];
  const float* Wst   = (const float*)d_in[7];
  const float* bst   = (const float*)d_in[8];
  const float* Wout  = (const float*)d_in[9];
  const float* bout  = (const float*)d_in[10];

  float* out  = (float*)d_out;                 // fp32: reference output dtype
  float* attn = out + (size_t)MR_ * DM_;       // output (4,194,304), then attn (67,108,864)

  u16*   x1b   = (u16*)d_ws;                    // [4096][512]
  u16*   Qh    = x1b   + (size_t)MR_ * DC_;     // [16][2048][64]
  u16*   Kh    = Qh    + (size_t)BH_ * L_ * DH_;
  u16*   KhT   = Kh    + (size_t)BH_ * L_ * DH_;// [16][64][2048]
  u16*   ctxb  = KhT   + (size_t)BH_ * DH_ * L_;// [4096][512]
  u16*   y2b   = ctxb  + (size_t)MR_ * DC_;     // [4096][512]
  u16*   Wqb   = y2b   + (size_t)MR_ * DC_;     // [512][512]
  u16*   Wkb   = Wqb   + (size_t)DC_ * DC_;
  u16*   Wstb  = Wkb   + (size_t)DC_ * DC_;
  u16*   Woutb = Wstb  + (size_t)DC_ * DC_;     // [1024][1024]
  float* salb  = (float*)(Woutb + (size_t)DM_ * DM_); // [16][2048]

  (void)in_sizes; (void)n_in; (void)out_size; (void)ws_size;

  cvt_k<<<dim3(3840), 256, 0, stream>>>(src, Wq, Wk, Wst, Wout,
                                        x1b, Wqb, Wkb, Wstb, Woutb);
  mgemm_k<0,64><<<dim3(8, 32), 256, 0, stream>>>(x1b, nullptr, Wqb, bq, nullptr, Qh, nullptr, DC_, DC_);
  mgemm_k<0,64><<<dim3(8, 32), 256, 0, stream>>>(x1b, nullptr, Wkb, bk, nullptr, Kh, nullptr, DC_, DC_);
  tr_k<<<dim3(512), 256, 0, stream>>>(Kh, KhT);
  conv_k<<<dim3(L_/32, B_), 256, 0, stream>>>(src, convw, convb, salb);
  attn_k<<<dim3(512), 256, 0, stream>>>(Qh, Kh, KhT, salb, attn, ctxb);
  mgemm_k<1,64><<<dim3(8, 32), 256, 0, stream>>>(ctxb, nullptr, Wstb, bst, src, y2b, nullptr, DC_, DC_);
  mgemm_k<2,128><<<dim3(8, 32), 256, 0, stream>>>(x1b, y2b, Woutb, bout, nullptr, nullptr, out, DM_, DM_);
}